// Round 13
// baseline (2920.036 us; speedup 1.0000x reference)
//
#include <hip/hip_runtime.h>

#define NN 50000
#define NE 800000
#define DD 128
#define BUCKETS 196   // ceil(NN/256) buckets of 256 nodes
#define PB 4096       // edges per partition block
#define PBLK 196      // ceil(NE/PB)
#define EMAX 6144     // per-bucket edge cap (mean 4096, sigma 64 -> +32 sigma)
#define GRID 1280     // 5 blocks/CU avg; capacity 6/CU (LDS 20.5K, VGPR<=85)
#define NTHR (GRID * 256)
#define NTILE 782     // ceil(NN/64) GEMM tiles
#define BSTR 72       // ushorts per col in sB quarter staging (64 + 8 pad)

typedef unsigned int uint_t;
typedef unsigned short ush_t;
typedef __attribute__((ext_vector_type(8))) short short8;   // 8 bf16
typedef __attribute__((ext_vector_type(4))) float f32x4;    // MFMA C/D

// bf16 helpers
__device__ __forceinline__ float bflo(uint_t u) { return __uint_as_float(u << 16); }
__device__ __forceinline__ float bfhi(uint_t u) { return __uint_as_float(u & 0xffff0000u); }
__device__ __forceinline__ ush_t f2bf(float f) {  // RNE
  uint_t u = __float_as_uint(f);
  u += 0x7fffu + ((u >> 16) & 1u);
  return (ush_t)(u >> 16);
}
__device__ __forceinline__ uint_t pack2(float a, float b) {
  return (uint_t)f2bf(a) | ((uint_t)f2bf(b) << 16);
}

__device__ __forceinline__ int ld_idx(const void* ei, int is64, long long i) {
  return is64 ? (int)((const long long*)ei)[i] : ((const int*)ei)[i];
}

// Per-wave index-width detect (int32 pairs seen as u64 have nonzero hi words).
__device__ __forceinline__ int detect64(const void* ei) {
  const unsigned long long* p = (const unsigned long long*)ei;
  unsigned long long w = p[threadIdx.x & 63];
  return __ballot((w >> 32) != 0) == 0ull ? 1 : 0;
}

// Block-wide inclusive scan over 256 ints.
__device__ __forceinline__ int block_incl_scan(int v, int tid, int* wsum) {
  int lane = tid & 63, wave = tid >> 6;
  int s = v;
#pragma unroll
  for (int off = 1; off < 64; off <<= 1) {
    int u = __shfl_up(s, off, 64);
    if (lane >= off) s += u;
  }
  if (lane == 63) wsum[wave] = s;
  __syncthreads();
  int base = 0;
  if (wave > 0) base += wsum[0];
  if (wave > 1) base += wsum[1];
  if (wave > 2) base += wsum[2];
  return base + s;
}

// Device-scope grid barrier -- FIXED from R12.
// R12 bug: pollers spun on atomicAdd(ptr,0) (an RMW); 1280 RMW-pollers
// serialized on one line and starved the arrival increments -> ~300 us per
// barrier. Now: arrival = one fetch_add per block; last arriver STOREs a
// flag (bar[8+ph]); pollers spin on device-scope atomic LOADs (concurrently
// serviceable) with ~0.85 us s_sleep backoff. Counters bar[0..5], flags
// bar[8..13] -- zeroed pre-launch. Safe: GRID 1280 < 6 blocks/CU * 256 CUs.
__device__ __forceinline__ void gridbar(int* bar, int ph) {
  __syncthreads();
  __threadfence();
  if (threadIdx.x == 0) {
    if (__hip_atomic_fetch_add(&bar[ph], 1, __ATOMIC_ACQ_REL,
                               __HIP_MEMORY_SCOPE_AGENT) == GRID - 1) {
      __hip_atomic_store(&bar[8 + ph], 1, __ATOMIC_RELEASE,
                         __HIP_MEMORY_SCOPE_AGENT);
    } else {
      while (!__hip_atomic_load(&bar[8 + ph], __ATOMIC_ACQUIRE,
                                __HIP_MEMORY_SCOPE_AGENT))
        __builtin_amdgcn_s_sleep(32);
    }
  }
  __syncthreads();
  __threadfence();
}

// Gather-mean phase: 16 lanes/node, uint4 loads, unroll x4, grid-stride.
__device__ __forceinline__ void agg_phase(const ush_t* __restrict__ featb,
                                          ush_t* __restrict__ meanb,
                                          const int* __restrict__ srclist,
                                          const int* __restrict__ offsets,
                                          int gtid) {
  for (int t0 = gtid; t0 < NN * 16; t0 += NTHR) {
    int node = t0 >> 4;
    int lane = t0 & 15;
    int f = lane << 3;
    int beg = offsets[node];
    int end = offsets[node + 1];
    float a0 = 0.f, a1 = 0.f, a2 = 0.f, a3 = 0.f,
          a4 = 0.f, a5 = 0.f, a6 = 0.f, a7 = 0.f;
    for (int c = beg; c < end; c += 16) {
      int idx = c + lane;
      int sl = (idx < end) ? srclist[idx] : 0;
      int m = min(16, end - c);
      int jj = 0;
      for (; jj + 4 <= m; jj += 4) {
        int s0 = __shfl(sl, jj, 16);
        int s1 = __shfl(sl, jj + 1, 16);
        int s2 = __shfl(sl, jj + 2, 16);
        int s3 = __shfl(sl, jj + 3, 16);
        uint4 v0 = *reinterpret_cast<const uint4*>(featb + (size_t)s0 * DD + f);
        uint4 v1 = *reinterpret_cast<const uint4*>(featb + (size_t)s1 * DD + f);
        uint4 v2 = *reinterpret_cast<const uint4*>(featb + (size_t)s2 * DD + f);
        uint4 v3 = *reinterpret_cast<const uint4*>(featb + (size_t)s3 * DD + f);
        a0 += bflo(v0.x); a1 += bfhi(v0.x); a2 += bflo(v0.y); a3 += bfhi(v0.y);
        a4 += bflo(v0.z); a5 += bfhi(v0.z); a6 += bflo(v0.w); a7 += bfhi(v0.w);
        a0 += bflo(v1.x); a1 += bfhi(v1.x); a2 += bflo(v1.y); a3 += bfhi(v1.y);
        a4 += bflo(v1.z); a5 += bfhi(v1.z); a6 += bflo(v1.w); a7 += bfhi(v1.w);
        a0 += bflo(v2.x); a1 += bfhi(v2.x); a2 += bflo(v2.y); a3 += bfhi(v2.y);
        a4 += bflo(v2.z); a5 += bfhi(v2.z); a6 += bflo(v2.w); a7 += bfhi(v2.w);
        a0 += bflo(v3.x); a1 += bfhi(v3.x); a2 += bflo(v3.y); a3 += bfhi(v3.y);
        a4 += bflo(v3.z); a5 += bfhi(v3.z); a6 += bflo(v3.w); a7 += bfhi(v3.w);
      }
      for (; jj < m; ++jj) {
        int s = __shfl(sl, jj, 16);
        uint4 v = *reinterpret_cast<const uint4*>(featb + (size_t)s * DD + f);
        a0 += bflo(v.x); a1 += bfhi(v.x); a2 += bflo(v.y); a3 += bfhi(v.y);
        a4 += bflo(v.z); a5 += bfhi(v.z); a6 += bflo(v.w); a7 += bfhi(v.w);
      }
    }
    float inv = 1.0f / fmaxf((float)(end - beg), 1.0f);
    uint4 o;
    o.x = pack2(a0 * inv, a1 * inv);
    o.y = pack2(a2 * inv, a3 * inv);
    o.z = pack2(a4 * inv, a5 * inv);
    o.w = pack2(a6 * inv, a7 * inv);
    *reinterpret_cast<uint4*>(meanb + (size_t)node * DD + f) = o;
  }
}

// MFMA GEMM phase: per tile of 64 rows x 128 cols, K=256 ([A0||A1] @ Wt).
// Wt staged in K-quarters (128 cols x 64 k, stride 72 ushorts, 18.4 KB).
// A-frags straight from global. Epilogue via lambda.
template <typename Epi>
__device__ __forceinline__ void sage_phase(int bid, int tid, int* smem,
                                           const ush_t* __restrict__ A0,
                                           const ush_t* __restrict__ A1,
                                           const ush_t* __restrict__ WT,
                                           Epi epi) {
  ush_t* sB = (ush_t*)smem;
  for (int tile = bid; tile < NTILE; tile += GRID) {
    int nb = tile * 64;
    int lane = tid & 63;
    int wave = tid >> 6;
    int n15 = lane & 15, quad = lane >> 4;
    int row = nb + wave * 16 + n15;
    int arow = (row < NN) ? row : (NN - 1);
    f32x4 acc[8];
#pragma unroll
    for (int t = 0; t < 8; ++t) acc[t] = (f32x4){0.f, 0.f, 0.f, 0.f};
    for (int q = 0; q < 4; ++q) {
      __syncthreads();
      for (int i = tid; i < 1024; i += 256) {  // 128 cols x 8 chunks of 8
        int col = i >> 3, cc = i & 7;
        *reinterpret_cast<short8*>(&sB[col * BSTR + cc * 8]) =
            *reinterpret_cast<const short8*>(WT + col * 256 + q * 64 + cc * 8);
      }
      __syncthreads();
      const ush_t* ap = (q < 2) ? (A0 + (size_t)arow * DD + q * 64)
                                : (A1 + (size_t)arow * DD + (q - 2) * 64);
#pragma unroll
      for (int c2 = 0; c2 < 2; ++c2) {
        int kl = c2 * 32 + quad * 8;
        short8 af = *reinterpret_cast<const short8*>(ap + kl);
#pragma unroll
        for (int t = 0; t < 8; ++t) {
          short8 bf = *reinterpret_cast<const short8*>(&sB[(t * 16 + n15) * BSTR + kl]);
          acc[t] = __builtin_amdgcn_mfma_f32_16x16x32_bf16(af, bf, acc[t], 0, 0, 0);
        }
      }
    }
    epi(nb, wave, quad, n15, acc);
  }
}

// ---------------------------------------------------------------------------
// The persistent mega kernel: all phases, separated by grid barriers.
// LDS union: partition 20.5 KB | gemm 18.4 KB | csr 2.1 KB -> 20.5 KB.
// ---------------------------------------------------------------------------
__global__ __launch_bounds__(256, 6) void mega_k(
    const void* __restrict__ ei, const float* __restrict__ x,
    const float* __restrict__ Wl1, const float* __restrict__ bl1,
    const float* __restrict__ Wr1, const float* __restrict__ Wl2,
    const float* __restrict__ bl2, const float* __restrict__ Wr2,
    const float* __restrict__ We, const float* __restrict__ be,
    int* __restrict__ bcur, int* __restrict__ bar, uint_t* __restrict__ pbuf,
    uint_t* __restrict__ epk, int* __restrict__ offsets,
    int* __restrict__ srclist, ush_t* __restrict__ xb,
    ush_t* __restrict__ meanb, ush_t* __restrict__ h1b,
    float2* __restrict__ s12, ush_t* __restrict__ Wt1,
    ush_t* __restrict__ Wt2, float* __restrict__ out) {
  __shared__ __align__(16) int smem[5128];
  int tid = threadIdx.x;
  int bid = blockIdx.x;
  int gtid = bid * 256 + tid;

  // ---- Phase AB: partition (blocks 0..195) || pack-x + wprep (rest) ----
  if (bid < PBLK) {
    int* hist = smem;
    int* basel = smem + 256;
    int* cur = smem + 512;
    int* gbase = smem + 768;
    int* wsum = smem + 1024;
    uint_t* buf = (uint_t*)(smem + 1028);  // full pv (bucket in bits 24-31)
    int is64 = detect64(ei);
    hist[tid] = 0;
    __syncthreads();
    long long base = (long long)bid * PB;
    uint_t pv[PB / 256];
#pragma unroll
    for (int i = 0; i < PB / 256; ++i) {
      long long e = base + i * 256 + tid;
      if (e < NE) {
        int s = ld_idx(ei, is64, e);
        int d = ld_idx(ei, is64, (long long)NE + e);
        pv[i] = ((uint_t)(d >> 8) << 24) | ((uint_t)(d & 255) << 16) | (uint_t)s;
        epk[e] = ((uint_t)d << 16) | (uint_t)s;
        atomicAdd(&hist[d >> 8], 1);
      } else {
        pv[i] = 0xFFFFFFFFu;
      }
    }
    __syncthreads();
    int hv = hist[tid];
    int incl = block_incl_scan(hv, tid, wsum);
    basel[tid] = incl - hv;
    cur[tid] = incl - hv;
    if (hv > 0) gbase[tid] = atomicAdd(&bcur[tid], hv);
    __syncthreads();
#pragma unroll
    for (int i = 0; i < PB / 256; ++i) {
      uint_t p = pv[i];
      if (p != 0xFFFFFFFFu) {
        int r = atomicAdd(&cur[p >> 24], 1);
        buf[r] = p;
      }
    }
    __syncthreads();
    int total = basel[255] + hist[255];
    for (int j = tid; j < total; j += 256) {
      uint_t p = buf[j];
      int b = p >> 24;
      int slot = gbase[b] + (j - basel[b]);
      if (slot < EMAX) pbuf[(size_t)b * EMAX + slot] = p;
    }
  } else {
    int at = (bid - PBLK) * 256 + tid;
    const int AT = (GRID - PBLK) * 256;
    for (int i = at; i < NN * DD / 4; i += AT) {  // pack x -> bf16
      float4 v = reinterpret_cast<const float4*>(x)[i];
      uint2 o;
      o.x = pack2(v.x, v.y);
      o.y = pack2(v.z, v.w);
      reinterpret_cast<uint2*>(xb)[i] = o;
    }
    for (int i = at; i < 65536; i += AT) {  // weight transpose+pack
      int layer = i >> 15;
      int r = i & 32767;
      int col = r >> 8;
      int k = r & 255;
      const float* Wl = layer ? Wl2 : Wl1;
      const float* Wr = layer ? Wr2 : Wr1;
      float v = (k < DD) ? Wl[k * DD + col] : Wr[(k - DD) * DD + col];
      (layer ? Wt2 : Wt1)[col * 256 + k] = f2bf(v);
    }
  }
  gridbar(bar, 0);

  // ---- Phase C: per-bucket CSR build (196 active blocks) ----
  if (bid < BUCKETS) {
    int* cnt = smem;
    int* scur = smem + 256;
    int* wsum = smem + 512;
    int* shd = smem + 516;  // sgb, scnt, stot
    int b = bid;
    int v = 0;
    if (tid < BUCKETS) {
      v = bcur[tid];
      if (v > EMAX) v = EMAX;
    }
    int incl = block_incl_scan(v, tid, wsum);
    if (tid == b) { shd[0] = incl - v; shd[1] = v; }
    if (tid == BUCKETS - 1) shd[2] = incl;
    cnt[tid] = 0;
    __syncthreads();
    int gb = shd[0], ecnt = shd[1];
    for (int j = tid; j < ecnt; j += 256)
      atomicAdd(&cnt[(pbuf[(size_t)b * EMAX + j] >> 16) & 255], 1);
    __syncthreads();
    int c = cnt[tid];
    int incl2 = block_incl_scan(c, tid, wsum);
    int ex = incl2 - c;
    scur[tid] = ex;
    int node = b * 256 + tid;
    if (node < NN) offsets[node] = gb + ex;
    if (b == BUCKETS - 1 && tid == 0) offsets[NN] = shd[2];
    __syncthreads();
    for (int j = tid; j < ecnt; j += 256) {  // re-read pbuf (L2-hot)
      uint_t e = pbuf[(size_t)b * EMAX + j];
      int p = atomicAdd(&scur[(e >> 16) & 255], 1);
      srclist[gb + p] = (int)(e & 0xFFFFu);
    }
  }
  gridbar(bar, 1);

  // ---- Phase D: agg1 (xb -> meanb) ----
  agg_phase(xb, meanb, srclist, offsets, gtid);
  gridbar(bar, 2);

  // ---- Phase E: sage1 -> h1b ----
  sage_phase(bid, tid, smem, meanb, xb, Wt1,
             [&](int nb, int wave, int quad, int n15, f32x4 (&acc)[8]) {
#pragma unroll
               for (int t = 0; t < 8; ++t) {
                 int col = t * 16 + n15;
                 float b = bl1[col];
#pragma unroll
                 for (int reg = 0; reg < 4; ++reg) {
                   int r = nb + wave * 16 + quad * 4 + reg;
                   if (r < NN)
                     h1b[(size_t)r * DD + col] = f2bf(fmaxf(acc[t][reg] + b, 0.f));
                 }
               }
             });
  gridbar(bar, 3);

  // ---- Phase F: agg2 (h1b -> meanb) ----
  agg_phase(h1b, meanb, srclist, offsets, gtid);
  gridbar(bar, 4);

  // ---- Phase G: sage2 + fused edge projection -> s12 ----
  sage_phase(bid, tid, smem, meanb, h1b, Wt2,
             [&](int nb, int wave, int quad, int n15, f32x4 (&acc)[8]) {
               float p1[4] = {0.f, 0.f, 0.f, 0.f};
               float p2[4] = {0.f, 0.f, 0.f, 0.f};
#pragma unroll
               for (int t = 0; t < 8; ++t) {
                 int col = t * 16 + n15;
                 float b = bl2[col];
                 float w1 = We[col];
                 float w2 = We[DD + col];
#pragma unroll
                 for (int reg = 0; reg < 4; ++reg) {
                   float v = acc[t][reg] + b;
                   p1[reg] += v * w1;
                   p2[reg] += v * w2;
                 }
               }
#pragma unroll
               for (int reg = 0; reg < 4; ++reg) {
                 float v1 = p1[reg], v2 = p2[reg];
                 for (int off = 8; off > 0; off >>= 1) {
                   v1 += __shfl_down(v1, off, 16);
                   v2 += __shfl_down(v2, off, 16);
                 }
                 int r = nb + wave * 16 + quad * 4 + reg;
                 if (n15 == 0 && r < NN) s12[r] = make_float2(v1, v2);
               }
             });
  gridbar(bar, 5);

  // ---- Phase H: edge scores ----
  for (int e = gtid; e < NE; e += NTHR) {
    uint_t p = epk[e];
    float2 a = s12[p & 0xFFFFu];  // src -> s1
    float2 b = s12[p >> 16];      // tgt -> s2
    float v = a.x + b.y + be[0];
    out[e] = 1.0f / (1.0f + __expf(-v));
  }
}

extern "C" void kernel_launch(void* const* d_in, const int* in_sizes, int n_in,
                              void* d_out, int out_size, void* d_ws, size_t ws_size,
                              hipStream_t stream) {
  const float* x   = (const float*)d_in[0];
  const void*  ei  = d_in[1];
  const float* Wl1 = (const float*)d_in[2];
  const float* bl1 = (const float*)d_in[3];
  const float* Wr1 = (const float*)d_in[4];
  const float* Wl2 = (const float*)d_in[5];
  const float* bl2 = (const float*)d_in[6];
  const float* Wr2 = (const float*)d_in[7];
  const float* We  = (const float*)d_in[8];
  const float* be  = (const float*)d_in[9];
  float* out = (float*)d_out;

  // Workspace (4B units, all sections multiples of 4 ints -> 16B aligned):
  // bcur[256] | bar[16] | offsets[50004] | epk[NE] | pbuf[BUCKETS*EMAX] |
  // srclist[NE] | xb | meanb | h1b | s12[2*NN] | Wt1 | Wt2   (~31 MB)
  int* bcur    = (int*)d_ws;
  int* bar     = bcur + 256;
  int* offsets = bar + 16;
  uint_t* epk  = (uint_t*)(offsets + 50004);
  uint_t* pbuf = epk + NE;
  int* srclist = (int*)(pbuf + (size_t)BUCKETS * EMAX);
  ush_t* xb    = (ush_t*)(srclist + NE);
  ush_t* meanb = xb + (size_t)NN * DD;
  ush_t* h1b   = meanb + (size_t)NN * DD;
  float2* s12  = (float2*)(h1b + (size_t)NN * DD);
  ush_t* Wt1   = (ush_t*)((float*)s12 + 2 * NN);
  ush_t* Wt2   = Wt1 + 32768;

  hipMemsetAsync(bcur, 0, (256 + 16) * sizeof(int), stream);
  mega_k<<<GRID, 256, 0, stream>>>(ei, x, Wl1, bl1, Wr1, Wl2, bl2, Wr2, We, be,
                                   bcur, bar, pbuf, epk, offsets, srclist, xb,
                                   meanb, h1b, s12, Wt1, Wt2, out);
}

// Round 14
// 222.113 us; speedup vs baseline: 13.1466x; 13.1466x over previous
//
#include <hip/hip_runtime.h>

#define NN 50000
#define NE 800000
#define DD 128
#define BUCKETS 196   // ceil(NN/256) buckets of 256 nodes
#define PB 4096       // edges per partition block
#define PBLK 196      // ceil(NE/PB)
#define EMAX 6144     // per-bucket edge cap (mean 4096, sigma 64 -> +32 sigma)
#define PACKB 6250    // x-pack blocks: NN*DD/4/256
#define BSTR 72       // ushorts per col in sB quarter staging (64 + 8 pad)

typedef unsigned int uint_t;
typedef unsigned short ush_t;
typedef __attribute__((ext_vector_type(8))) short short8;   // 8 bf16
typedef __attribute__((ext_vector_type(4))) float f32x4;    // MFMA C/D

// bf16 helpers
__device__ __forceinline__ float bflo(uint_t u) { return __uint_as_float(u << 16); }
__device__ __forceinline__ float bfhi(uint_t u) { return __uint_as_float(u & 0xffff0000u); }
__device__ __forceinline__ ush_t f2bf(float f) {  // RNE
  uint_t u = __float_as_uint(f);
  u += 0x7fffu + ((u >> 16) & 1u);
  return (ush_t)(u >> 16);
}
__device__ __forceinline__ uint_t pack2(float a, float b) {
  return (uint_t)f2bf(a) | ((uint_t)f2bf(b) << 16);
}

__device__ __forceinline__ int ld_idx(const void* ei, int is64, long long i) {
  return is64 ? (int)((const long long*)ei)[i] : ((const int*)ei)[i];
}

// Per-wave index-width detect (int32 pairs seen as u64 have nonzero hi words).
__device__ __forceinline__ int detect64(const void* ei) {
  const unsigned long long* p = (const unsigned long long*)ei;
  unsigned long long w = p[threadIdx.x & 63];
  return __ballot((w >> 32) != 0) == 0ull ? 1 : 0;
}

// Block-wide inclusive scan over 256 ints.
__device__ __forceinline__ int block_incl_scan(int v, int tid, int* wsum) {
  int lane = tid & 63, wave = tid >> 6;
  int s = v;
#pragma unroll
  for (int off = 1; off < 64; off <<= 1) {
    int u = __shfl_up(s, off, 64);
    if (lane >= off) s += u;
  }
  if (lane == 63) wsum[wave] = s;
  __syncthreads();
  int base = 0;
  if (wave > 0) base += wsum[0];
  if (wave > 1) base += wsum[1];
  if (wave > 2) base += wsum[2];
  return base + s;
}

// ---------------------------------------------------------------------------
// Fused prep+partition kernel (R9-verified).
//   blocks [0, PBLK):            partition edges into bucket slots + emit epk
//   blocks [PBLK, PBLK+PACKB):   pack x fp32->bf16
//   blocks [PBLK+PACKB, +256):   weight transpose+pack (Wt[col][k], K=256)
// ---------------------------------------------------------------------------
__global__ __launch_bounds__(256) void prep_part_k(
    const void* __restrict__ ei, int* __restrict__ bcur,
    uint_t* __restrict__ pbuf, uint_t* __restrict__ epk,
    const float* __restrict__ x, ush_t* __restrict__ xb,
    const float* __restrict__ Wl1, const float* __restrict__ Wr1,
    const float* __restrict__ Wl2, const float* __restrict__ Wr2,
    ush_t* __restrict__ Wt1, ush_t* __restrict__ Wt2) {
  __shared__ int hist[256];
  __shared__ int basel[256];
  __shared__ int cur[256];
  __shared__ int gbase[256];
  __shared__ int wsum[4];
  __shared__ uint_t buf[PB];
  __shared__ unsigned char bbuf[PB];
  int tid = threadIdx.x;
  int blk = blockIdx.x;
  if (blk >= PBLK) {
    blk -= PBLK;
    if (blk < PACKB) {  // pack x
      int i = blk * 256 + tid;
      float4 v = reinterpret_cast<const float4*>(x)[i];
      uint2 o;
      o.x = pack2(v.x, v.y);
      o.y = pack2(v.z, v.w);
      reinterpret_cast<uint2*>(xb)[i] = o;
      return;
    }
    blk -= PACKB;  // weight transpose: blk in [0,256)
    int e = blk * 256 + tid;  // < 65536
    int layer = e >> 15;
    int r = e & 32767;
    int col = r >> 8;
    int k = r & 255;
    const float* Wl = layer ? Wl2 : Wl1;
    const float* Wr = layer ? Wr2 : Wr1;
    float v = (k < DD) ? Wl[k * DD + col] : Wr[(k - DD) * DD + col];
    ush_t* Wt = layer ? Wt2 : Wt1;
    Wt[col * 256 + k] = f2bf(v);
    return;
  }
  // ---- partition region ----
  int is64 = detect64(ei);
  hist[tid] = 0;
  __syncthreads();
  long long base = (long long)blk * PB;
  uint_t pv[PB / 256];
#pragma unroll
  for (int i = 0; i < PB / 256; ++i) {
    long long e = base + i * 256 + tid;
    if (e < NE) {
      int s = ld_idx(ei, is64, e);
      int d = ld_idx(ei, is64, (long long)NE + e);
      pv[i] = ((uint_t)(d >> 8) << 24) | ((uint_t)(d & 255) << 16) | (uint_t)s;
      epk[e] = ((uint_t)d << 16) | (uint_t)s;  // original-order compact edges
      atomicAdd(&hist[d >> 8], 1);
    } else {
      pv[i] = 0xFFFFFFFFu;
    }
  }
  __syncthreads();
  int hv = hist[tid];
  int incl = block_incl_scan(hv, tid, wsum);
  basel[tid] = incl - hv;
  cur[tid] = incl - hv;
  if (hv > 0) gbase[tid] = atomicAdd(&bcur[tid], hv);
  __syncthreads();
#pragma unroll
  for (int i = 0; i < PB / 256; ++i) {
    uint_t p = pv[i];
    if (p != 0xFFFFFFFFu) {
      int b = p >> 24;
      int r = atomicAdd(&cur[b], 1);
      buf[r] = p & 0xFFFFFFu;
      bbuf[r] = (unsigned char)b;
    }
  }
  __syncthreads();
  int total = basel[255] + hist[255];
  for (int j = tid; j < total; j += 256) {
    int b = bbuf[j];
    int slot = gbase[b] + (j - basel[b]);
    if (slot < EMAX) pbuf[(size_t)b * EMAX + slot] = buf[j];
  }
}

// ---------------------------------------------------------------------------
// Per-bucket CSR build (one block per bucket), single-CU scatter.
// ---------------------------------------------------------------------------
__global__ __launch_bounds__(256) void csr_k(const uint_t* __restrict__ pbuf,
                                             const int* __restrict__ bcur,
                                             int* __restrict__ offsets,
                                             int* __restrict__ srclist) {
  __shared__ int cnt[256];
  __shared__ int scur[256];
  __shared__ int wsum[4];
  __shared__ int sgb, scnt, stot;
  __shared__ uint_t ebuf[EMAX];
  int tid = threadIdx.x;
  int b = blockIdx.x;
  int v = 0;
  if (tid < BUCKETS) {
    v = bcur[tid];
    if (v > EMAX) v = EMAX;
  }
  int incl = block_incl_scan(v, tid, wsum);
  if (tid == b) { sgb = incl - v; scnt = v; }
  if (tid == BUCKETS - 1) stot = incl;
  cnt[tid] = 0;
  __syncthreads();
  int gb = sgb;
  int ecnt = scnt;
  for (int j = tid; j < ecnt; j += 256) {
    uint_t e = pbuf[(size_t)b * EMAX + j];
    ebuf[j] = e;
    atomicAdd(&cnt[(e >> 16) & 255], 1);
  }
  __syncthreads();
  int c = cnt[tid];
  int incl2 = block_incl_scan(c, tid, wsum);
  int ex = incl2 - c;
  scur[tid] = ex;
  int node = b * 256 + tid;
  if (node < NN) offsets[node] = gb + ex;
  if (b == BUCKETS - 1 && tid == 0) offsets[NN] = stot;
  __syncthreads();
  for (int j = tid; j < ecnt; j += 256) {
    uint_t e = ebuf[j];
    int p = atomicAdd(&scur[(e >> 16) & 255], 1);
    srclist[gb + p] = (int)(e & 0xFFFFu);
  }
}

// ---------------------------------------------------------------------------
// Gather-mean over bf16 features (R9-verified): 16 lanes/node, uint4 loads,
// srclist chunked 16-wide + shuffle broadcast, unroll x4.
// ---------------------------------------------------------------------------
__global__ __launch_bounds__(256) void agg_k(const ush_t* __restrict__ featb,
                                             const int* __restrict__ srclist,
                                             const int* __restrict__ offsets,
                                             ush_t* __restrict__ meanb) {
  int t = blockIdx.x * 256 + threadIdx.x;
  int node = t >> 4;
  int lane = t & 15;
  int f = lane << 3;  // 8 ushorts = 16 B
  int beg = offsets[node];
  int end = offsets[node + 1];
  float a0 = 0.f, a1 = 0.f, a2 = 0.f, a3 = 0.f, a4 = 0.f, a5 = 0.f, a6 = 0.f, a7 = 0.f;
  for (int c = beg; c < end; c += 16) {
    int idx = c + lane;
    int sl = (idx < end) ? srclist[idx] : 0;
    int m = min(16, end - c);
    int jj = 0;
    for (; jj + 4 <= m; jj += 4) {
      int s0 = __shfl(sl, jj, 16);
      int s1 = __shfl(sl, jj + 1, 16);
      int s2 = __shfl(sl, jj + 2, 16);
      int s3 = __shfl(sl, jj + 3, 16);
      uint4 v0 = *reinterpret_cast<const uint4*>(featb + (size_t)s0 * DD + f);
      uint4 v1 = *reinterpret_cast<const uint4*>(featb + (size_t)s1 * DD + f);
      uint4 v2 = *reinterpret_cast<const uint4*>(featb + (size_t)s2 * DD + f);
      uint4 v3 = *reinterpret_cast<const uint4*>(featb + (size_t)s3 * DD + f);
      a0 += bflo(v0.x); a1 += bfhi(v0.x); a2 += bflo(v0.y); a3 += bfhi(v0.y);
      a4 += bflo(v0.z); a5 += bfhi(v0.z); a6 += bflo(v0.w); a7 += bfhi(v0.w);
      a0 += bflo(v1.x); a1 += bfhi(v1.x); a2 += bflo(v1.y); a3 += bfhi(v1.y);
      a4 += bflo(v1.z); a5 += bfhi(v1.z); a6 += bflo(v1.w); a7 += bfhi(v1.w);
      a0 += bflo(v2.x); a1 += bfhi(v2.x); a2 += bflo(v2.y); a3 += bfhi(v2.y);
      a4 += bflo(v2.z); a5 += bfhi(v2.z); a6 += bflo(v2.w); a7 += bfhi(v2.w);
      a0 += bflo(v3.x); a1 += bfhi(v3.x); a2 += bflo(v3.y); a3 += bfhi(v3.y);
      a4 += bflo(v3.z); a5 += bfhi(v3.z); a6 += bflo(v3.w); a7 += bfhi(v3.w);
    }
    for (; jj < m; ++jj) {
      int s = __shfl(sl, jj, 16);
      uint4 v = *reinterpret_cast<const uint4*>(featb + (size_t)s * DD + f);
      a0 += bflo(v.x); a1 += bfhi(v.x); a2 += bflo(v.y); a3 += bfhi(v.y);
      a4 += bflo(v.z); a5 += bfhi(v.z); a6 += bflo(v.w); a7 += bfhi(v.w);
    }
  }
  float inv = 1.0f / fmaxf((float)(end - beg), 1.0f);
  uint4 o;
  o.x = pack2(a0 * inv, a1 * inv);
  o.y = pack2(a2 * inv, a3 * inv);
  o.z = pack2(a4 * inv, a5 * inv);
  o.w = pack2(a6 * inv, a7 * inv);
  *reinterpret_cast<uint4*>(meanb + (size_t)node * DD + f) = o;
}

// ---------------------------------------------------------------------------
// MFMA GEMM core, quarter-staged B (mega-verified in R12/R13): per block one
// tile of 64 rows x 128 cols, K=256 ([A0||A1] @ Wt). Wt staged in K-quarters
// (128 cols x 64 k, stride 72 ushorts, 18.4 KB LDS -> 6 blocks/CU vs R9's
// 67.6 KB/2 blocks). A-frags straight from global.
// ---------------------------------------------------------------------------
#define MFMA_CORE_Q(A0PTR, A1PTR, WTPTR)                                       \
  int tid = threadIdx.x;                                                       \
  int lane = tid & 63;                                                         \
  int wave = tid >> 6;                                                         \
  int n15 = lane & 15, quad = lane >> 4;                                       \
  int nb = blockIdx.x * 64;                                                    \
  int row = nb + wave * 16 + n15;                                              \
  int arow = (row < NN) ? row : (NN - 1);                                      \
  f32x4 acc[8];                                                                \
  _Pragma("unroll")                                                            \
  for (int t = 0; t < 8; ++t) acc[t] = (f32x4){0.f, 0.f, 0.f, 0.f};            \
  for (int q = 0; q < 4; ++q) {                                                \
    __syncthreads();                                                           \
    for (int i = tid; i < 1024; i += 256) { /* 128 cols x 8 chunks of 8 */     \
      int col = i >> 3, cc = i & 7;                                            \
      *reinterpret_cast<short8*>(&sB[col * BSTR + cc * 8]) =                   \
          *reinterpret_cast<const short8*>(WTPTR + col * 256 + q * 64 + cc * 8); \
    }                                                                          \
    __syncthreads();                                                           \
    const ush_t* ap = (q < 2) ? (A0PTR + (size_t)arow * DD + q * 64)           \
                              : (A1PTR + (size_t)arow * DD + (q - 2) * 64);    \
    _Pragma("unroll")                                                          \
    for (int c2 = 0; c2 < 2; ++c2) {                                           \
      int kl = c2 * 32 + quad * 8;                                             \
      short8 af = *reinterpret_cast<const short8*>(ap + kl);                   \
      _Pragma("unroll")                                                        \
      for (int t = 0; t < 8; ++t) {                                            \
        short8 bf = *reinterpret_cast<const short8*>(&sB[(t * 16 + n15) * BSTR + kl]); \
        acc[t] = __builtin_amdgcn_mfma_f32_16x16x32_bf16(af, bf, acc[t], 0, 0, 0); \
      }                                                                        \
    }                                                                          \
  }

// ---------------------------------------------------------------------------
// Layer 1: h1 = relu([mean||x] @ Wt1 + bl1), bf16 out.
// C/D: col = lane&15 (+16t), row = quad*4 + reg.
// ---------------------------------------------------------------------------
__global__ __launch_bounds__(256, 6) void sage_l1(
    const ush_t* __restrict__ meanb, const ush_t* __restrict__ xb,
    const ush_t* __restrict__ Wt1, const float* __restrict__ bl,
    ush_t* __restrict__ h1b) {
  __shared__ __align__(16) ush_t sB[128 * BSTR];
  MFMA_CORE_Q(meanb, xb, Wt1)
#pragma unroll
  for (int t = 0; t < 8; ++t) {
    int col = t * 16 + n15;
    float b = bl[col];
#pragma unroll
    for (int reg = 0; reg < 4; ++reg) {
      int r = nb + wave * 16 + quad * 4 + reg;
      if (r < NN)
        h1b[(size_t)r * DD + col] = f2bf(fmaxf(acc[t][reg] + b, 0.f));
    }
  }
}

// ---------------------------------------------------------------------------
// Layer 2 + fused edge projection; s12[i] = (h2[i].We[:128], h2[i].We[128:]).
// ---------------------------------------------------------------------------
__global__ __launch_bounds__(256, 6) void sage_l2(
    const ush_t* __restrict__ meanb, const ush_t* __restrict__ h1b,
    const ush_t* __restrict__ Wt2, const float* __restrict__ bl,
    const float* __restrict__ We, float2* __restrict__ s12) {
  __shared__ __align__(16) ush_t sB[128 * BSTR];
  MFMA_CORE_Q(meanb, h1b, Wt2)
  float p1[4] = {0.f, 0.f, 0.f, 0.f};
  float p2[4] = {0.f, 0.f, 0.f, 0.f};
#pragma unroll
  for (int t = 0; t < 8; ++t) {
    int col = t * 16 + n15;
    float b = bl[col];
    float w1 = We[col];
    float w2 = We[DD + col];
#pragma unroll
    for (int reg = 0; reg < 4; ++reg) {
      float v = acc[t][reg] + b;
      p1[reg] += v * w1;
      p2[reg] += v * w2;
    }
  }
#pragma unroll
  for (int reg = 0; reg < 4; ++reg) {
    float v1 = p1[reg], v2 = p2[reg];
    for (int off = 8; off > 0; off >>= 1) {
      v1 += __shfl_down(v1, off, 16);
      v2 += __shfl_down(v2, off, 16);
    }
    int r = nb + wave * 16 + quad * 4 + reg;
    if (n15 == 0 && r < NN) s12[r] = make_float2(v1, v2);
  }
}

// ---------------------------------------------------------------------------
// Edge scores from compact edges: y = sigmoid(s1[src] + s2[tgt] + be).
// ---------------------------------------------------------------------------
__global__ __launch_bounds__(256) void edge_k(const uint_t* __restrict__ epk,
                                              const float2* __restrict__ s12,
                                              const float* __restrict__ be,
                                              float* __restrict__ out) {
  int e = blockIdx.x * 256 + threadIdx.x;
  uint_t p = epk[e];
  float2 a = s12[p & 0xFFFFu];   // src -> s1
  float2 b = s12[p >> 16];       // tgt -> s2
  float v = a.x + b.y + be[0];
  out[e] = 1.0f / (1.0f + __expf(-v));
}

extern "C" void kernel_launch(void* const* d_in, const int* in_sizes, int n_in,
                              void* d_out, int out_size, void* d_ws, size_t ws_size,
                              hipStream_t stream) {
  const float* x   = (const float*)d_in[0];
  const void*  ei  = d_in[1];
  const float* Wl1 = (const float*)d_in[2];
  const float* bl1 = (const float*)d_in[3];
  const float* Wr1 = (const float*)d_in[4];
  const float* Wl2 = (const float*)d_in[5];
  const float* bl2 = (const float*)d_in[6];
  const float* Wr2 = (const float*)d_in[7];
  const float* We  = (const float*)d_in[8];
  const float* be  = (const float*)d_in[9];
  float* out = (float*)d_out;

  // Workspace (4B units, every section 16B-aligned):
  // bcur[256] | offsets[50004] | epk[NE] | pbuf[BUCKETS*EMAX] | srclist[NE] |
  // xb[NN*DD/2] | meanb | h1b | s12[2*NN] | Wt1[16384] | Wt2[16384]
  int* bcur    = (int*)d_ws;
  int* offsets = bcur + 256;
  uint_t* epk  = (uint_t*)(offsets + 50004);
  uint_t* pbuf = epk + NE;
  int* srclist = (int*)(pbuf + (size_t)BUCKETS * EMAX);
  ush_t* xb    = (ush_t*)(srclist + NE);
  ush_t* meanb = xb + (size_t)NN * DD;
  ush_t* h1b   = meanb + (size_t)NN * DD;
  float2* s12  = (float2*)(h1b + (size_t)NN * DD);
  ush_t* Wt1   = (ush_t*)((float*)s12 + 2 * NN);
  ush_t* Wt2   = Wt1 + 32768;

  hipMemsetAsync(bcur, 0, 256 * sizeof(int), stream);
  prep_part_k<<<PBLK + PACKB + 256, 256, 0, stream>>>(
      ei, bcur, pbuf, epk, x, xb, Wl1, Wr1, Wl2, Wr2, Wt1, Wt2);
  csr_k<<<BUCKETS, 256, 0, stream>>>(pbuf, bcur, offsets, srclist);

  int gemm_blocks = (NN + 63) / 64;  // 782
  agg_k<<<(NN * 16) / 256, 256, 0, stream>>>(xb, srclist, offsets, meanb);
  sage_l1<<<gemm_blocks, 256, 0, stream>>>(meanb, xb, Wt1, bl1, h1b);

  agg_k<<<(NN * 16) / 256, 256, 0, stream>>>(h1b, srclist, offsets, meanb);
  sage_l2<<<gemm_blocks, 256, 0, stream>>>(meanb, h1b, Wt2, bl2, We, s12);

  edge_k<<<NE / 256, 256, 0, stream>>>(epk, s12, be, out);
}